// Round 4
// baseline (743.068 us; speedup 1.0000x reference)
//
#include <hip/hip_runtime.h>
#include <hip/hip_bf16.h>

#define USER_NUM 50000
#define ITEM_NUM 20000
#define NNODE    70000
#define DD       64
#define SCAN_T   1024
#define NB_U     1280
#define NB_I     512

__device__ __forceinline__ const float* feat_row(const float* __restrict__ ue,
                                                 const float* __restrict__ ie, int n) {
    return (n < USER_NUM) ? (ue + (size_t)n * DD)
                          : (ie + (size_t)(n - USER_NUM) * DD);
}

// ---- CSR build: histogram -> block scan -> scatter -------------------------

__global__ __launch_bounds__(256) void hist_kernel(const int* __restrict__ erow,
                                                   int* __restrict__ cnt, int E) {
    const int stride = gridDim.x * blockDim.x;
    for (int e = blockIdx.x * blockDim.x + threadIdx.x; e < E; e += stride)
        atomicAdd(&cnt[erow[e]], 1);
}

__global__ __launch_bounds__(SCAN_T) void scan_kernel(const int* __restrict__ cnt,
                                                      int* __restrict__ base) {
    __shared__ int s[SCAN_T];
    const int t = threadIdx.x;
    const int CH = (NNODE + SCAN_T - 1) / SCAN_T;   // 69
    const int lo = t * CH;
    const int hi = min(lo + CH, NNODE);
    int sum = 0;
    for (int i = lo; i < hi; ++i) sum += cnt[i];
    s[t] = sum;
    __syncthreads();
    for (int off = 1; off < SCAN_T; off <<= 1) {
        int v = s[t];
        int u = (t >= off) ? s[t - off] : 0;
        __syncthreads();
        s[t] = v + u;
        __syncthreads();
    }
    int running = s[t] - sum;
    for (int i = lo; i < hi; ++i) {
        base[i] = running;
        running += cnt[i];
    }
    if (t == SCAN_T - 1) base[NNODE] = s[SCAN_T - 1];
}

__global__ __launch_bounds__(256) void scatter_kernel(
    const int* __restrict__ erow, const int* __restrict__ ecol,
    const float* __restrict__ eval, const int* __restrict__ base,
    int* __restrict__ cursor, int2* __restrict__ epair, int E) {
    const int stride = gridDim.x * blockDim.x;
    for (int e = blockIdx.x * blockDim.x + threadIdx.x; e < E; e += stride) {
        const int r = erow[e];
        const int pos = atomicAdd(&cursor[r], 1);
        epair[base[r] + pos] = make_int2(ecol[e], __float_as_int(eval[e]));
    }
}

// ---- SpMM, gather form, scalarized edge stream -----------------------------

__global__ __launch_bounds__(256) void spmm_kernel(
    const float* __restrict__ ue, const float* __restrict__ ie,
    const int2* __restrict__ epair, const int* __restrict__ base,
    float* __restrict__ lx, float* __restrict__ lx2) {
    const int lane = threadIdx.x & 63;
    int wv = (int)((blockIdx.x * blockDim.x + threadIdx.x) >> 6);
    wv = __builtin_amdgcn_readfirstlane(wv);
    const int nw = (int)((gridDim.x * blockDim.x) >> 6);
    for (int r = wv; r < NNODE; r += nw) {
        const int jb = base[r];
        const int je = base[r + 1];
        float acc1 = 0.f, acc2 = 0.f;
        int j = jb;
        for (; j + 4 <= je; j += 4) {
            const int2 p0 = epair[j + 0];
            const int2 p1 = epair[j + 1];
            const int2 p2 = epair[j + 2];
            const int2 p3 = epair[j + 3];
            const float f0 = feat_row(ue, ie, p0.x)[lane];
            const float f1 = feat_row(ue, ie, p1.x)[lane];
            const float f2 = feat_row(ue, ie, p2.x)[lane];
            const float f3 = feat_row(ue, ie, p3.x)[lane];
            const float v0 = __int_as_float(p0.y);
            const float v1 = __int_as_float(p1.y);
            const float v2 = __int_as_float(p2.y);
            const float v3 = __int_as_float(p3.y);
            acc1 = fmaf(v0, f0, acc1); acc2 = fmaf(v0 * f0, f0, acc2);
            acc1 = fmaf(v1, f1, acc1); acc2 = fmaf(v1 * f1, f1, acc2);
            acc1 = fmaf(v2, f2, acc1); acc2 = fmaf(v2 * f2, f2, acc2);
            acc1 = fmaf(v3, f3, acc1); acc2 = fmaf(v3 * f3, f3, acc2);
        }
        for (; j < je; ++j) {
            const int2 p = epair[j];
            const float f = feat_row(ue, ie, p.x)[lane];
            const float v = __int_as_float(p.y);
            acc1 = fmaf(v, f, acc1);
            acc2 = fmaf(v * f, f, acc2);
        }
        lx [(size_t)r * DD + lane] = acc1;
        lx2[(size_t)r * DD + lane] = acc2;
    }
}

// ---- Fused GCN transform + per-node MLP-layer1 partial ---------------------
// h = leaky_relu((lx+f)@Wg1 + bg1 + lx2@Wg2 + bg2)   (kept in registers)
// user n<USER:  part[n] = f@W1[0:64]   + h@W1[64:128]  + b1
// item:         part[n] = f@W1[128:192]+ h@W1[192:256]
// Grid is partitioned: blocks [0,NB_U) do users, [NB_U,NB_U+NB_I) do items,
// so each block stages only its 32KB half of W1 (total LDS 64KB).
// NOTE: part aliases lx (row read before written by the owning wave only).

__global__ __launch_bounds__(256) void transform_part_kernel(
    const float* __restrict__ ue, const float* __restrict__ ie,
    const float* lx, const float* lx2,
    const float* __restrict__ Wg1, const float* __restrict__ bg1,
    const float* __restrict__ Wg2, const float* __restrict__ bg2,
    const float* __restrict__ W1, const float* __restrict__ b1,
    float* part) {
    __shared__ float sWg1[DD * DD];
    __shared__ float sWg2[DD * DD];
    __shared__ float sWa[DD * DD];
    __shared__ float sWb[DD * DD];
    const bool is_user = blockIdx.x < NB_U;
    const float* W1h = W1 + (is_user ? 0 : 2 * DD * DD);
    for (int i = threadIdx.x; i < DD * DD; i += 256) {
        sWg1[i] = Wg1[i];
        sWg2[i] = Wg2[i];
        sWa[i]  = W1h[i];
        sWb[i]  = W1h[DD * DD + i];
    }
    __syncthreads();
    const int lane = threadIdx.x & 63;
    const int w    = threadIdx.x >> 6;
    const float biasg = bg1[lane] + bg2[lane];
    const float bias1 = is_user ? b1[lane] : 0.f;

    const int lwave  = (is_user ? blockIdx.x : (blockIdx.x - NB_U)) * 4 + w;
    const int nwav   = (is_user ? NB_U : NB_I) * 4;
    const int count  = is_user ? USER_NUM : ITEM_NUM;
    const int nbase  = is_user ? 0 : USER_NUM;
    const float* fb  = is_user ? ue : ie;

    for (int idx = lwave; idx < count; idx += nwav) {
        const int n = nbase + idx;
        const float f  = fb[(size_t)idx * DD + lane];
        const float a1 = lx[(size_t)n * DD + lane] + f;
        const float a2 = lx2[(size_t)n * DD + lane];
        float o1 = biasg, o2 = 0.f;
#pragma unroll
        for (int k = 0; k < DD; ++k) {
            o1 = fmaf(__shfl(a1, k), sWg1[k * DD + lane], o1);
            o2 = fmaf(__shfl(a2, k), sWg2[k * DD + lane], o2);
        }
        const float x = o1 + o2;
        const float h = (x > 0.f) ? x : 0.01f * x;
        float pa = bias1, pb = 0.f;
#pragma unroll
        for (int k = 0; k < DD; ++k) {
            pa = fmaf(__shfl(f, k), sWa[k * DD + lane], pa);
            pb = fmaf(__shfl(h, k), sWb[k * DD + lane], pb);
        }
        part[(size_t)n * DD + lane] = pa + pb;
    }
}

// ---- Per-sample MLP: o1 = relu(part_u + part_i); layers 2,3 ----------------

__global__ __launch_bounds__(256) void mlp_kernel(
    const float* __restrict__ part,
    const float* __restrict__ W2, const float* __restrict__ b2,
    const float* __restrict__ W3, const float* __restrict__ b3,
    const int* __restrict__ uid, const int* __restrict__ iid,
    float* __restrict__ out, int B) {
    __shared__ float sW2[DD * 32];
    __shared__ float sW3[32];
    for (int i = threadIdx.x; i < DD * 32; i += 256) sW2[i] = W2[i];
    if (threadIdx.x < 32) sW3[threadIdx.x] = W3[threadIdx.x];
    __syncthreads();
    const int lane = threadIdx.x & 63;
    const int wave = (int)((blockIdx.x * blockDim.x + threadIdx.x) >> 6);
    const int nw   = (int)((gridDim.x * blockDim.x) >> 6);
    const float bias2 = b2[lane & 31];
    const float w3v   = sW3[lane & 31];
    const float bias3 = b3[0];
    for (int s = wave; s < B; s += nw) {
        const int u  = uid[s];
        const int it = iid[s];
        const float pu = part[(size_t)u * DD + lane];
        const float pi = part[(size_t)(USER_NUM + it) * DD + lane];
        const float x  = pu + pi;
        const float o1 = (x > 0.f) ? x : 0.f;
        float acc_a = bias2, acc_b = 0.f;
#pragma unroll
        for (int k = 0; k < DD; k += 2) {
            acc_a = fmaf(__shfl(o1, k),     sW2[k * 32 + (lane & 31)],       acc_a);
            acc_b = fmaf(__shfl(o1, k + 1), sW2[(k + 1) * 32 + (lane & 31)], acc_b);
        }
        const float a2 = acc_a + acc_b;
        const float o2 = (a2 > 0.f) ? a2 : 0.f;
        float p = o2 * w3v;
        p += __shfl_xor(p, 1);
        p += __shfl_xor(p, 2);
        p += __shfl_xor(p, 4);
        p += __shfl_xor(p, 8);
        p += __shfl_xor(p, 16);
        if (lane == 0) out[s] = p + bias3;
    }
}

extern "C" void kernel_launch(void* const* d_in, const int* in_sizes, int n_in,
                              void* d_out, int out_size, void* d_ws, size_t ws_size,
                              hipStream_t stream) {
    const float* ue   = (const float*)d_in[0];
    const float* ie   = (const float*)d_in[1];
    const int*   erow = (const int*)d_in[2];
    const int*   ecol = (const int*)d_in[3];
    const float* evalp= (const float*)d_in[4];
    const float* Wg1  = (const float*)d_in[5];
    const float* bg1  = (const float*)d_in[6];
    const float* Wg2  = (const float*)d_in[7];
    const float* bg2  = (const float*)d_in[8];
    const float* W1   = (const float*)d_in[9];
    const float* b1   = (const float*)d_in[10];
    const float* W2   = (const float*)d_in[11];
    const float* b2   = (const float*)d_in[12];
    const float* W3   = (const float*)d_in[13];
    const float* b3   = (const float*)d_in[14];
    const int*   uid  = (const int*)d_in[15];
    const int*   iid  = (const int*)d_in[16];
    float* out = (float*)d_out;

    const int E = in_sizes[2];
    const int B = in_sizes[15];

    // workspace: [lx 17.92MB][lx2 17.92MB][epair 16MB][cnt][cursor][base]
    // part aliases lx.
    char* ws = (char*)d_ws;
    const size_t nd = (size_t)NNODE * DD;
    float* lx    = (float*)ws;
    float* part  = lx;                                      // alias
    float* lx2   = lx + nd;
    int2*  epair = (int2*)(ws + 2 * nd * sizeof(float));
    int*   cnt   = (int*)(ws + 2 * nd * sizeof(float) + (size_t)E * sizeof(int2));
    int*   cursor= cnt + NNODE;
    int*   base  = cursor + NNODE;

    hipMemsetAsync(cnt, 0, 2 * NNODE * sizeof(int), stream);

    hist_kernel<<<2048, 256, 0, stream>>>(erow, cnt, E);
    scan_kernel<<<1, SCAN_T, 0, stream>>>(cnt, base);
    scatter_kernel<<<2048, 256, 0, stream>>>(erow, ecol, evalp, base, cursor, epair, E);
    spmm_kernel<<<4096, 256, 0, stream>>>(ue, ie, epair, base, lx, lx2);
    transform_part_kernel<<<NB_U + NB_I, 256, 0, stream>>>(
        ue, ie, lx, lx2, Wg1, bg1, Wg2, bg2, W1, b1, part);
    mlp_kernel<<<1024, 256, 0, stream>>>(part, W2, b2, W3, b3, uid, iid, out, B);
}

// Round 5
// 584.298 us; speedup vs baseline: 1.2717x; 1.2717x over previous
//
#include <hip/hip_runtime.h>
#include <hip/hip_bf16.h>

#define USER_NUM 50000
#define ITEM_NUM 20000
#define NNODE    70000
#define DD       64
#define SCAN_T   1024
#define NB_U2    1000
#define NB_I2    400

__device__ __forceinline__ const float* feat_row(const float* __restrict__ ue,
                                                 const float* __restrict__ ie, int n) {
    return (n < USER_NUM) ? (ue + (size_t)n * DD)
                          : (ie + (size_t)(n - USER_NUM) * DD);
}

// ---- CSR build: histogram -> block scan -> scatter -------------------------

__global__ __launch_bounds__(256) void hist_kernel(const int* __restrict__ erow,
                                                   int* __restrict__ cnt, int E) {
    const int stride = gridDim.x * blockDim.x;
    for (int e = blockIdx.x * blockDim.x + threadIdx.x; e < E; e += stride)
        atomicAdd(&cnt[erow[e]], 1);
}

__global__ __launch_bounds__(SCAN_T) void scan_kernel(const int* __restrict__ cnt,
                                                      int* __restrict__ base) {
    __shared__ int s[SCAN_T];
    const int t = threadIdx.x;
    const int CH = (NNODE + SCAN_T - 1) / SCAN_T;   // 69
    const int lo = t * CH;
    const int hi = min(lo + CH, NNODE);
    int sum = 0;
    for (int i = lo; i < hi; ++i) sum += cnt[i];
    s[t] = sum;
    __syncthreads();
    for (int off = 1; off < SCAN_T; off <<= 1) {
        int v = s[t];
        int u = (t >= off) ? s[t - off] : 0;
        __syncthreads();
        s[t] = v + u;
        __syncthreads();
    }
    int running = s[t] - sum;
    for (int i = lo; i < hi; ++i) {
        base[i] = running;
        running += cnt[i];
    }
    if (t == SCAN_T - 1) base[NNODE] = s[SCAN_T - 1];
}

// cursor pre-initialized to base (d2d copy) -> atomicAdd yields absolute slot.
__global__ __launch_bounds__(256) void scatter_kernel(
    const int* __restrict__ erow, const int* __restrict__ ecol,
    const float* __restrict__ eval,
    int* __restrict__ cursor, int2* __restrict__ epair, int E) {
    const int stride = gridDim.x * blockDim.x;
    for (int e = blockIdx.x * blockDim.x + threadIdx.x; e < E; e += stride) {
        const int pos = atomicAdd(&cursor[erow[e]], 1);
        epair[pos] = make_int2(ecol[e], __float_as_int(eval[e]));
    }
}

// ---- SpMM, gather form, scalarized edge stream -----------------------------
// Stores a1 = lx + f (self term folded in) and a2 = lx2.

__global__ __launch_bounds__(256) void spmm_kernel(
    const float* __restrict__ ue, const float* __restrict__ ie,
    const int2* __restrict__ epair, const int* __restrict__ base,
    float* __restrict__ lx, float* __restrict__ lx2) {
    const int lane = threadIdx.x & 63;
    int wv = (int)((blockIdx.x * blockDim.x + threadIdx.x) >> 6);
    wv = __builtin_amdgcn_readfirstlane(wv);
    const int nw = (int)((gridDim.x * blockDim.x) >> 6);
    for (int r = wv; r < NNODE; r += nw) {
        const int jb = base[r];
        const int je = base[r + 1];
        float acc1 = 0.f, acc2 = 0.f;
        int j = jb;
        for (; j + 4 <= je; j += 4) {
            const int2 p0 = epair[j + 0];
            const int2 p1 = epair[j + 1];
            const int2 p2 = epair[j + 2];
            const int2 p3 = epair[j + 3];
            const float f0 = feat_row(ue, ie, p0.x)[lane];
            const float f1 = feat_row(ue, ie, p1.x)[lane];
            const float f2 = feat_row(ue, ie, p2.x)[lane];
            const float f3 = feat_row(ue, ie, p3.x)[lane];
            const float v0 = __int_as_float(p0.y);
            const float v1 = __int_as_float(p1.y);
            const float v2 = __int_as_float(p2.y);
            const float v3 = __int_as_float(p3.y);
            acc1 = fmaf(v0, f0, acc1); acc2 = fmaf(v0 * f0, f0, acc2);
            acc1 = fmaf(v1, f1, acc1); acc2 = fmaf(v1 * f1, f1, acc2);
            acc1 = fmaf(v2, f2, acc1); acc2 = fmaf(v2 * f2, f2, acc2);
            acc1 = fmaf(v3, f3, acc1); acc2 = fmaf(v3 * f3, f3, acc2);
        }
        for (; j < je; ++j) {
            const int2 p = epair[j];
            const float f = feat_row(ue, ie, p.x)[lane];
            const float v = __int_as_float(p.y);
            acc1 = fmaf(v, f, acc1);
            acc2 = fmaf(v * f, f, acc2);
        }
        lx [(size_t)r * DD + lane] = acc1 + feat_row(ue, ie, r)[lane];
        lx2[(size_t)r * DD + lane] = acc2;
    }
}

// ---- GCN transform, zero-LDS: weights in VGPRs, activations via s_load -----
// h = leaky_relu(a1@Wg1 + a2@Wg2 + bg1 + bg2); h aliases a1 (row-safe).

__global__ __launch_bounds__(256) void gcn_h_kernel(
    const float* a1, const float* a2,
    const float* __restrict__ Wg1, const float* __restrict__ bg1,
    const float* __restrict__ Wg2, const float* __restrict__ bg2,
    float* h) {
    const int lane = threadIdx.x & 63;
    float w1[DD], w2[DD];
#pragma unroll
    for (int k = 0; k < DD; ++k) {
        w1[k] = Wg1[k * DD + lane];
        w2[k] = Wg2[k * DD + lane];
    }
    const float bias = bg1[lane] + bg2[lane];
    int wv = (int)((blockIdx.x * blockDim.x + threadIdx.x) >> 6);
    wv = __builtin_amdgcn_readfirstlane(wv);
    const int nw = (int)((gridDim.x * blockDim.x) >> 6);
    for (int r = wv; r < NNODE; r += nw) {
        const float* ar = a1 + (size_t)r * DD;
        const float* br = a2 + (size_t)r * DD;
        float o0 = bias, o1 = 0.f, o2 = 0.f, o3 = 0.f;
#pragma unroll
        for (int k = 0; k < DD; k += 2) {
            o0 = fmaf(ar[k],     w1[k],     o0);
            o1 = fmaf(ar[k + 1], w1[k + 1], o1);
            o2 = fmaf(br[k],     w2[k],     o2);
            o3 = fmaf(br[k + 1], w2[k + 1], o3);
        }
        const float x = (o0 + o1) + (o2 + o3);
        h[(size_t)r * DD + lane] = (x > 0.f) ? x : 0.01f * x;
    }
}

// ---- Per-node MLP layer-1 partial, zero-LDS --------------------------------
// user: part[n] = f@W1[0:64]   + h@W1[64:128]  + b1
// item: part[n] = f@W1[128:192]+ h@W1[192:256]
// part aliases a2/lx2 (not read here). Grid split by node type.

__global__ __launch_bounds__(256) void part_kernel(
    const float* __restrict__ ue, const float* __restrict__ ie,
    const float* h,
    const float* __restrict__ W1, const float* __restrict__ b1,
    float* part) {
    const bool is_user = blockIdx.x < NB_U2;
    const float* Wh = W1 + (is_user ? 0 : 2 * DD * DD);
    const int lane = threadIdx.x & 63;
    float wa[DD], wb[DD];
#pragma unroll
    for (int k = 0; k < DD; ++k) {
        wa[k] = Wh[k * DD + lane];
        wb[k] = Wh[(DD + k) * DD + lane];
    }
    const float bias = is_user ? b1[lane] : 0.f;
    const float* fb  = is_user ? ue : ie;
    const int count  = is_user ? USER_NUM : ITEM_NUM;
    const int nbase  = is_user ? 0 : USER_NUM;
    const int nwav   = (is_user ? NB_U2 : NB_I2) * 4;
    int lw = (is_user ? blockIdx.x : blockIdx.x - NB_U2) * 4 + (int)(threadIdx.x >> 6);
    lw = __builtin_amdgcn_readfirstlane(lw);
    for (int idx = lw; idx < count; idx += nwav) {
        const float* fr = fb + (size_t)idx * DD;
        const float* hr = h + (size_t)(nbase + idx) * DD;
        float p0 = bias, p1 = 0.f, p2 = 0.f, p3 = 0.f;
#pragma unroll
        for (int k = 0; k < DD; k += 2) {
            p0 = fmaf(fr[k],     wa[k],     p0);
            p1 = fmaf(fr[k + 1], wa[k + 1], p1);
            p2 = fmaf(hr[k],     wb[k],     p2);
            p3 = fmaf(hr[k + 1], wb[k + 1], p3);
        }
        part[(size_t)(nbase + idx) * DD + lane] = (p0 + p1) + (p2 + p3);
    }
}

// ---- Per-sample MLP: o1 = relu(part_u + part_i); layers 2,3 ----------------

__global__ __launch_bounds__(256) void mlp_kernel(
    const float* __restrict__ part,
    const float* __restrict__ W2, const float* __restrict__ b2,
    const float* __restrict__ W3, const float* __restrict__ b3,
    const int* __restrict__ uid, const int* __restrict__ iid,
    float* __restrict__ out, int B) {
    __shared__ float sW2[DD * 32];
    __shared__ float sW3[32];
    for (int i = threadIdx.x; i < DD * 32; i += 256) sW2[i] = W2[i];
    if (threadIdx.x < 32) sW3[threadIdx.x] = W3[threadIdx.x];
    __syncthreads();
    const int lane = threadIdx.x & 63;
    const int wave = (int)((blockIdx.x * blockDim.x + threadIdx.x) >> 6);
    const int nw   = (int)((gridDim.x * blockDim.x) >> 6);
    const float bias2 = b2[lane & 31];
    const float w3v   = sW3[lane & 31];
    const float bias3 = b3[0];
    for (int s = wave; s < B; s += nw) {
        const int u  = uid[s];
        const int it = iid[s];
        const float pu = part[(size_t)u * DD + lane];
        const float pi = part[(size_t)(USER_NUM + it) * DD + lane];
        const float x  = pu + pi;
        const float o1 = (x > 0.f) ? x : 0.f;
        float acc_a = bias2, acc_b = 0.f;
#pragma unroll
        for (int k = 0; k < DD; k += 2) {
            acc_a = fmaf(__shfl(o1, k),     sW2[k * 32 + (lane & 31)],       acc_a);
            acc_b = fmaf(__shfl(o1, k + 1), sW2[(k + 1) * 32 + (lane & 31)], acc_b);
        }
        const float a2 = acc_a + acc_b;
        const float o2 = (a2 > 0.f) ? a2 : 0.f;
        float p = o2 * w3v;
        p += __shfl_xor(p, 1);
        p += __shfl_xor(p, 2);
        p += __shfl_xor(p, 4);
        p += __shfl_xor(p, 8);
        p += __shfl_xor(p, 16);
        if (lane == 0) out[s] = p + bias3;
    }
}

extern "C" void kernel_launch(void* const* d_in, const int* in_sizes, int n_in,
                              void* d_out, int out_size, void* d_ws, size_t ws_size,
                              hipStream_t stream) {
    const float* ue   = (const float*)d_in[0];
    const float* ie   = (const float*)d_in[1];
    const int*   erow = (const int*)d_in[2];
    const int*   ecol = (const int*)d_in[3];
    const float* evalp= (const float*)d_in[4];
    const float* Wg1  = (const float*)d_in[5];
    const float* bg1  = (const float*)d_in[6];
    const float* Wg2  = (const float*)d_in[7];
    const float* bg2  = (const float*)d_in[8];
    const float* W1   = (const float*)d_in[9];
    const float* b1   = (const float*)d_in[10];
    const float* W2   = (const float*)d_in[11];
    const float* b2   = (const float*)d_in[12];
    const float* W3   = (const float*)d_in[13];
    const float* b3   = (const float*)d_in[14];
    const int*   uid  = (const int*)d_in[15];
    const int*   iid  = (const int*)d_in[16];
    float* out = (float*)d_out;

    const int E = in_sizes[2];
    const int B = in_sizes[15];

    // workspace: [lx 17.92MB][lx2 17.92MB][epair 16MB][cnt][cursor][base]
    // h aliases lx; part aliases lx2.
    char* ws = (char*)d_ws;
    const size_t nd = (size_t)NNODE * DD;
    float* lx    = (float*)ws;
    float* h     = lx;                                      // alias (row-safe)
    float* lx2   = lx + nd;
    float* part  = lx2;                                     // alias (lx2 dead)
    int2*  epair = (int2*)(ws + 2 * nd * sizeof(float));
    int*   cnt   = (int*)(ws + 2 * nd * sizeof(float) + (size_t)E * sizeof(int2));
    int*   cursor= cnt + NNODE;
    int*   base  = cursor + NNODE;

    hipMemsetAsync(cnt, 0, NNODE * sizeof(int), stream);

    hist_kernel<<<2048, 256, 0, stream>>>(erow, cnt, E);
    scan_kernel<<<1, SCAN_T, 0, stream>>>(cnt, base);
    hipMemcpyAsync(cursor, base, NNODE * sizeof(int), hipMemcpyDeviceToDevice, stream);
    scatter_kernel<<<2048, 256, 0, stream>>>(erow, ecol, evalp, cursor, epair, E);
    spmm_kernel<<<4096, 256, 0, stream>>>(ue, ie, epair, base, lx, lx2);
    gcn_h_kernel<<<1024, 256, 0, stream>>>(lx, lx2, Wg1, bg1, Wg2, bg2, h);
    part_kernel<<<NB_U2 + NB_I2, 256, 0, stream>>>(ue, ie, h, W1, b1, part);
    mlp_kernel<<<1024, 256, 0, stream>>>(part, W2, b2, W3, b3, uid, iid, out, B);
}